// Round 2
// baseline (43578.979 us; speedup 1.0000x reference)
//
#include <hip/hip_runtime.h>
#include <hip/hip_bf16.h>
#include <math.h>

// Problem dims
#define PP 400
#define QQ 30
#define BB 32
#define EE 300
#define HH 300
#define FF 300
#define AA 30
#define LL 2

typedef unsigned short ushort_t;
typedef unsigned int uint_t;

// ---------------------------------------------------------------------------
// Embedding gather: out[row, e] = embed[tok[row], e]
__global__ void gather_embed(const int* __restrict__ tok,
                             const float* __restrict__ embed,
                             float* __restrict__ out, int n_tok) {
    int i = blockIdx.x * blockDim.x + threadIdx.x;
    int n = n_tok * EE;
    if (i >= n) return;
    int row = i / EE, e = i - row * EE;
    out[i] = embed[(size_t)tok[row] * EE + e];
}

// ---------------------------------------------------------------------------
// C[M,N] = A[M,K] @ Bw[N,K]^T + bias[N], optional relu.
#define BM 64
#define BN 64
#define BK 16
__global__ void gemm_nt_bias(const float* __restrict__ A,
                             const float* __restrict__ Bw,
                             const float* __restrict__ bias,
                             float* __restrict__ C,
                             int M, int N, int K, int relu) {
    __shared__ float As[BK][BM];
    __shared__ float Bs[BK][BN];
    int tid = threadIdx.x;
    int row0 = blockIdx.y * BM;
    int col0 = blockIdx.x * BN;
    int tx = tid & 15, ty = tid >> 4;
    int lm = tid >> 2;          // 0..63
    int lk = (tid & 3) * 4;     // 0,4,8,12
    float acc[4][4] = {{0.f}};
    for (int k0 = 0; k0 < K; k0 += BK) {
        float4 av = make_float4(0.f, 0.f, 0.f, 0.f);
        int ar = row0 + lm;
        int kk = k0 + lk;
        if (ar < M) {
            if (kk + 3 < K) {
                av = *(const float4*)(A + (size_t)ar * K + kk);
            } else {
                float t0 = (kk + 0 < K) ? A[(size_t)ar * K + kk + 0] : 0.f;
                float t1 = (kk + 1 < K) ? A[(size_t)ar * K + kk + 1] : 0.f;
                float t2 = (kk + 2 < K) ? A[(size_t)ar * K + kk + 2] : 0.f;
                float t3 = (kk + 3 < K) ? A[(size_t)ar * K + kk + 3] : 0.f;
                av = make_float4(t0, t1, t2, t3);
            }
        }
        As[lk + 0][lm] = av.x; As[lk + 1][lm] = av.y;
        As[lk + 2][lm] = av.z; As[lk + 3][lm] = av.w;

        float4 bv = make_float4(0.f, 0.f, 0.f, 0.f);
        int br = col0 + lm;
        if (br < N) {
            if (kk + 3 < K) {
                bv = *(const float4*)(Bw + (size_t)br * K + kk);
            } else {
                float t0 = (kk + 0 < K) ? Bw[(size_t)br * K + kk + 0] : 0.f;
                float t1 = (kk + 1 < K) ? Bw[(size_t)br * K + kk + 1] : 0.f;
                float t2 = (kk + 2 < K) ? Bw[(size_t)br * K + kk + 2] : 0.f;
                float t3 = (kk + 3 < K) ? Bw[(size_t)br * K + kk + 3] : 0.f;
                bv = make_float4(t0, t1, t2, t3);
            }
        }
        Bs[lk + 0][lm] = bv.x; Bs[lk + 1][lm] = bv.y;
        Bs[lk + 2][lm] = bv.z; Bs[lk + 3][lm] = bv.w;
        __syncthreads();
        #pragma unroll
        for (int k = 0; k < BK; k++) {
            float a[4], b[4];
            #pragma unroll
            for (int i = 0; i < 4; i++) a[i] = As[k][ty * 4 + i];
            #pragma unroll
            for (int j = 0; j < 4; j++) b[j] = Bs[k][tx * 4 + j];
            #pragma unroll
            for (int i = 0; i < 4; i++) {
                #pragma unroll
                for (int j = 0; j < 4; j++) acc[i][j] += a[i] * b[j];
            }
        }
        __syncthreads();
    }
    #pragma unroll
    for (int i = 0; i < 4; i++) {
        int r = row0 + ty * 4 + i;
        if (r >= M) continue;
        #pragma unroll
        for (int j = 0; j < 4; j++) {
            int c = col0 + tx * 4 + j;
            if (c >= N) continue;
            float v = acc[i][j] + bias[c];
            if (relu) v = fmaxf(v, 0.f);
            C[(size_t)r * N + c] = v;
        }
    }
}

// ---------------------------------------------------------------------------
// scores + softmax over q per (p,b)
__global__ void scores_softmax(const float* __restrict__ ffp,
                               const float* __restrict__ ffq,
                               const float* __restrict__ p_mask,
                               const float* __restrict__ q_mask,
                               float* __restrict__ weights) {
    int blk = blockIdx.x;          // p*BB + b
    int p = blk / BB, b = blk - p * BB;
    __shared__ float fp[FF];
    __shared__ float sq[QQ];
    for (int f = threadIdx.x; f < FF; f += blockDim.x)
        fp[f] = ffp[(size_t)(p * BB + b) * FF + f];
    __syncthreads();
    int q = threadIdx.x;
    if (q < QQ) {
        const float* fq = ffq + (size_t)(q * BB + b) * FF;
        float s = 0.f;
        for (int f = 0; f < FF; f++) s += fp[f] * fq[f];
        s *= p_mask[p * BB + b] * q_mask[q * BB + b];
        sq[q] = s;
    }
    __syncthreads();
    if (q < QQ) {
        float m = -INFINITY;
        for (int k = 0; k < QQ; k++) m = fmaxf(m, sq[k]);
        float sum = 0.f;
        for (int k = 0; k < QQ; k++) sum += expf(sq[k] - m);
        weights[(size_t)b * PP * QQ + p * QQ + q] = expf(sq[q] - m) / sum;
    }
}

// ---------------------------------------------------------------------------
__global__ void align_concat(const float* __restrict__ weights,
                             const float* __restrict__ q_emb,
                             const float* __restrict__ p_emb,
                             float* __restrict__ x0) {
    int blk = blockIdx.x;          // p*BB + b
    int p = blk / BB, b = blk - p * BB;
    __shared__ float w[QQ];
    if (threadIdx.x < QQ)
        w[threadIdx.x] = weights[(size_t)b * PP * QQ + p * QQ + threadIdx.x];
    __syncthreads();
    for (int e = threadIdx.x; e < EE; e += blockDim.x) {
        float acc = 0.f;
        for (int q = 0; q < QQ; q++)
            acc += w[q] * q_emb[(size_t)(q * BB + b) * EE + e];
        size_t base = (size_t)(p * BB + b) * (2 * EE);
        x0[base + e] = p_emb[(size_t)(p * BB + b) * EE + e];
        x0[base + EE + e] = acc;
    }
}

// ---------------------------------------------------------------------------
// w_hh fp32 [4][900][300] -> bf16 (RNE) same layout
__global__ void convert_whh_bf16(const float* __restrict__ w,
                                 ushort_t* __restrict__ o) {
    int i = blockIdx.x * blockDim.x + threadIdx.x;
    if (i >= 4 * 900 * 300) return;
    uint_t u = __float_as_uint(w[i]);
    uint_t r = (u + 0x7fffu + ((u >> 16) & 1u)) >> 16;
    o[i] = (ushort_t)r;
}

// zero h double-buffers (both layers) and group counters
__global__ void init_gru(float* __restrict__ hbuf, int* __restrict__ cnt) {
    int i = blockIdx.x * blockDim.x + threadIdx.x;
    if (i < 2 * 2 * 2 * BB * HH) hbuf[i] = 0.f;
    if (i < 2 * 32 * 16) cnt[i] = 0;
}

// ---------------------------------------------------------------------------
// Persistent BiGRU layer: 400 steps in one launch.
// Grid = 320 blocks: 32 groups (2 dirs x 16 batch-pairs) x 10 blocks.
// Each block owns j-slice [j0, j0+30) for its 2 batches; its 90 w_hh rows
// (r/z/n gates) live in LDS as bf16 (row stride 151 dwords -> conflict-free).
// Per step, groups exchange h via a double-buffered global buffer guarded by
// a per-group counter (release add / acquire spin + threadfence).
#define GBLK 10
__global__ __launch_bounds__(256, 1) void gru_layer(
        const float* __restrict__ xp_f,   // [400][32][900]
        const float* __restrict__ xp_b,   // [400][32][900]
        const ushort_t* __restrict__ wbf, // [2][900][300] bf16, this layer
        const float* __restrict__ bhh,    // [2][900], this layer
        float* __restrict__ hbuf,         // [2][2][32][300], this layer
        int* __restrict__ cnts,           // [32][16], this layer
        float* __restrict__ out) {        // [400][32][600]
    int gid = blockIdx.x;
    int group = gid / GBLK;          // 0..31
    int blkin = gid - group * GBLK;  // 0..9
    int dir = group >> 4;
    int b0 = (group & 15) * 2;
    int j0 = blkin * 30;
    const float* xp = dir ? xp_b : xp_f;
    const float* bhh_d = bhh + dir * 900;
    int* cnt = cnts + group * 16;

    __shared__ ushort_t sW[90 * 302];    // row stride 302 bf16 = 151 dwords
    __shared__ float sh[2][300];
    __shared__ float sgh[2][90];
    uint_t* sWu = (uint_t*)sW;

    int tid = threadIdx.x;

    // one-time: stage this block's 90 weight rows into LDS
    {
        const uint_t* wsrc = (const uint_t*)(wbf + (size_t)dir * 270000);
        for (int d = tid; d < 90 * 150; d += 256) {
            int r = d / 150, k = d - r * 150;
            int gr = (r < 30) ? (j0 + r)
                   : (r < 60) ? (300 + j0 + r - 30)
                              : (600 + j0 + r - 60);
            sWu[r * 151 + k] = wsrc[gr * 150 + k];
        }
    }
    // per-thread constants
    int bb = tid / 90, rr = tid - (tid / 90) * 90;   // dot phase (tid<180)
    float bias = 0.f;
    if (tid < 180) {
        int gr = (rr < 30) ? (j0 + rr)
               : (rr < 60) ? (300 + j0 + rr - 30)
                           : (600 + j0 + rr - 60);
        bias = bhh_d[gr];
    }
    __syncthreads();

    for (int s = 0; s < PP; s++) {
        int te = dir ? (PP - 1 - s) : s;
        // prefetch this step's xp gate inputs (independent of h / sync)
        float xrv = 0.f, xzv = 0.f, xnv = 0.f;
        if (tid < 60) {
            const float* xq = xp + ((size_t)te * BB + (b0 + tid / 30)) * 900
                              + j0 + (tid - (tid / 30) * 30);
            xrv = xq[0]; xzv = xq[300]; xnv = xq[600];
        }
        // wait for h[s&1] to be complete
        if (s > 0) {
            if (tid == 0) {
                while (__hip_atomic_load(cnt, __ATOMIC_ACQUIRE,
                                         __HIP_MEMORY_SCOPE_AGENT) < GBLK * s)
                    __builtin_amdgcn_s_sleep(4);
            }
            __syncthreads();
            __threadfence();
        }
        // stage h (600 contiguous floats for our 2 batches)
        {
            const float* hr = hbuf + (size_t)(s & 1) * (2 * BB * HH)
                              + (size_t)(dir * BB + b0) * HH;
            for (int d = tid; d < 600; d += 256)
                sh[d / 300][d - (d / 300) * 300] = hr[d];
        }
        __syncthreads();
        // 90 rows x 2 batches of 300-MAC dots, weights from LDS (bf16)
        if (tid < 180) {
            const uint_t* wrow = sWu + rr * 151;
            const float2* hp = (const float2*)sh[bb];
            float acc = 0.f;
            #pragma unroll 10
            for (int k = 0; k < 150; k++) {
                uint_t wp = wrow[k];
                float2 hv = hp[k];
                acc = fmaf(__uint_as_float(wp << 16), hv.x, acc);
                acc = fmaf(__uint_as_float(wp & 0xffff0000u), hv.y, acc);
            }
            sgh[bb][rr] = acc + bias;
        }
        __syncthreads();
        // gate math + h update for our 60 (b,j) pairs
        if (tid < 60) {
            int gb = tid / 30, jj = tid - gb * 30;
            int bg = b0 + gb;
            float r = 1.f / (1.f + expf(-(xrv + sgh[gb][jj])));
            float z = 1.f / (1.f + expf(-(xzv + sgh[gb][30 + jj])));
            float n = tanhf(xnv + r * sgh[gb][60 + jj]);
            float hn = (1.f - z) * n + z * sh[gb][j0 + jj];
            hbuf[(size_t)((s + 1) & 1) * (2 * BB * HH)
                 + (size_t)(dir * BB + bg) * HH + j0 + jj] = hn;
            out[((size_t)te * BB + bg) * (2 * HH) + dir * HH + j0 + jj] = hn;
        }
        __threadfence();
        __syncthreads();
        if (tid == 0)
            __hip_atomic_fetch_add(cnt, 1, __ATOMIC_RELEASE,
                                   __HIP_MEMORY_SCOPE_AGENT);
    }
}

// ---------------------------------------------------------------------------
__global__ void span_score(const float* __restrict__ stt,
                           const float* __restrict__ endv,
                           const float* __restrict__ w_a,
                           const int* __restrict__ p_lens,
                           float* __restrict__ final_) {
    int blk = blockIdx.x;          // p*BB + b
    int p = blk / BB, b = blk - p * BB;
    __shared__ float ss[FF];
    __shared__ float wa[FF];
    for (int f = threadIdx.x; f < FF; f += blockDim.x) {
        ss[f] = stt[(size_t)(p * BB + b) * FF + f];
        wa[f] = w_a[f];
    }
    __syncthreads();
    int lane = threadIdx.x & 63, wv = threadIdx.x >> 6;
    int plen = p_lens[b];
    for (int j = wv; j < AA; j += 2) {
        float acc = 0.f;
        int pe = p + j;
        if (pe < PP) {
            const float* ev = endv + (size_t)(pe * BB + b) * FF;
            for (int f = lane; f < FF; f += 64)
                acc += fmaxf(ss[f] + ev[f], 0.f) * wa[f];
        } else {
            for (int f = lane; f < FF; f += 64)
                acc += fmaxf(ss[f], 0.f) * wa[f];
        }
        #pragma unroll
        for (int off = 32; off; off >>= 1) acc += __shfl_down(acc, off);
        if (lane == 0) {
            float v = (pe < plen) ? acc : 0.f;
            final_[(size_t)b * (PP * AA) + p * AA + j] = v;
        }
    }
}

// ---------------------------------------------------------------------------
__global__ void log_softmax_rows(float* __restrict__ out,
                                 const float* __restrict__ final_, int n) {
    int b = blockIdx.x;
    const float* row = final_ + (size_t)b * n;
    __shared__ float red[256];
    float m = -INFINITY;
    for (int i = threadIdx.x; i < n; i += 256) m = fmaxf(m, row[i]);
    red[threadIdx.x] = m;
    __syncthreads();
    for (int s = 128; s; s >>= 1) {
        if (threadIdx.x < s) red[threadIdx.x] = fmaxf(red[threadIdx.x], red[threadIdx.x + s]);
        __syncthreads();
    }
    m = red[0];
    __syncthreads();
    float sum = 0.f;
    for (int i = threadIdx.x; i < n; i += 256) sum += expf(row[i] - m);
    red[threadIdx.x] = sum;
    __syncthreads();
    for (int s = 128; s; s >>= 1) {
        if (threadIdx.x < s) red[threadIdx.x] += red[threadIdx.x + s];
        __syncthreads();
    }
    float lse = m + logf(red[0]);
    for (int i = threadIdx.x; i < n; i += 256) out[(size_t)b * n + i] = row[i] - lse;
}

// ---------------------------------------------------------------------------
extern "C" void kernel_launch(void* const* d_in, const int* in_sizes, int n_in,
                              void* d_out, int out_size, void* d_ws, size_t ws_size,
                              hipStream_t stream) {
    (void)in_sizes; (void)n_in; (void)out_size; (void)ws_size;
    const int*   p_tok  = (const int*)d_in[0];
    const int*   q_tok  = (const int*)d_in[1];
    const float* p_mask = (const float*)d_in[2];
    const float* q_mask = (const float*)d_in[3];
    const int*   p_lens = (const int*)d_in[4];
    const float* embed   = (const float*)d_in[6];
    const float* w_align = (const float*)d_in[7];
    const float* b_align = (const float*)d_in[8];
    const float* w_ih    = (const float*)d_in[9];    // [2,2,900,600]
    const float* w_hh    = (const float*)d_in[10];   // [2,2,900,300]
    const float* b_ih    = (const float*)d_in[11];   // [2,2,900]
    const float* b_hh    = (const float*)d_in[12];   // [2,2,900]
    const float* w_stt   = (const float*)d_in[13];
    const float* b_stt   = (const float*)d_in[14];
    const float* w_end   = (const float*)d_in[15];
    const float* b_end   = (const float*)d_in[16];
    const float* w_a     = (const float*)d_in[17];
    float* out = (float*)d_out;
    float* ws = (float*)d_ws;

    size_t off = 0;
    float* p_emb = ws + off;  off += (size_t)PP * BB * EE;       // 3,840,000
    float* ff_p  = ws + off;  off += (size_t)PP * BB * FF;       // 3,840,000
    float* q_emb = ws + off;  off += (size_t)QQ * BB * EE;       //   288,000
    float* ff_q  = ws + off;  off += (size_t)QQ * BB * FF;       //   288,000
    float* scores= ws + off;  off += (size_t)BB * PP * QQ;       //   384,000
    float* x0    = ws + off;  off += (size_t)PP * BB * 2 * EE;   // 7,680,000
    float* xp_f  = ws + off;  off += (size_t)PP * BB * 900;      // 11,520,000
    float* xp_b  = ws + off;  off += (size_t)PP * BB * 900;      // 11,520,000
    ushort_t* wbf = (ushort_t*)(ws + off); off += 540000;        // 4*900*300 bf16
    float* hbuf  = ws + off;  off += (size_t)2 * 2 * 2 * BB * HH; //  76,800
    int*   cnts  = (int*)(ws + off); off += 2 * 32 * 16;         //     1,024
    float* x1    = p_emb;       // aliases p_emb+ff_p (dead by GRU time)
    float* sttb  = xp_f;        // aliases xp (dead after layer-2 recurrence)
    float* endb  = xp_f + (size_t)PP * BB * FF;
    float* finalb= scores;

    const int M = PP * BB;      // 12800
    const int Mq = QQ * BB;     // 960

    // prep: bf16 recurrent weights + zero h/counters
    convert_whh_bf16<<<(4 * 900 * 300 + 255) / 256, 256, 0, stream>>>(w_hh, wbf);
    init_gru<<<(2 * 2 * 2 * BB * HH + 255) / 256, 256, 0, stream>>>(hbuf, cnts);

    // 1. embedding gathers
    gather_embed<<<(M * EE + 255) / 256, 256, 0, stream>>>(p_tok, embed, p_emb, M);
    gather_embed<<<(Mq * EE + 255) / 256, 256, 0, stream>>>(q_tok, embed, q_emb, Mq);

    // 2. aligned-attention projections (relu)
    gemm_nt_bias<<<dim3((FF + BN - 1) / BN, (M + BM - 1) / BM), 256, 0, stream>>>(
        p_emb, w_align, b_align, ff_p, M, FF, EE, 1);
    gemm_nt_bias<<<dim3((FF + BN - 1) / BN, (Mq + BM - 1) / BM), 256, 0, stream>>>(
        q_emb, w_align, b_align, ff_q, Mq, FF, EE, 1);

    // 3. scores + softmax over q
    scores_softmax<<<PP * BB, 64, 0, stream>>>(ff_p, ff_q, p_mask, q_mask, scores);

    // 4. q_align + concat -> x0 = p_star [P,B,600]
    align_concat<<<PP * BB, 256, 0, stream>>>(scores, q_emb, p_emb, x0);

    // 5. BiGRU, 2 layers: batched xp GEMMs + one persistent kernel per layer
    for (int l = 0; l < LL; l++) {
        const float* xin = (l == 0) ? x0 : x1;
        float* xout = (l == 0) ? x1 : x0;
        gemm_nt_bias<<<dim3((900 + BN - 1) / BN, (M + BM - 1) / BM), 256, 0, stream>>>(
            xin, w_ih + (size_t)(l * 2 + 0) * 900 * 600, b_ih + (l * 2 + 0) * 900,
            xp_f, M, 900, 600, 0);
        gemm_nt_bias<<<dim3((900 + BN - 1) / BN, (M + BM - 1) / BM), 256, 0, stream>>>(
            xin, w_ih + (size_t)(l * 2 + 1) * 900 * 600, b_ih + (l * 2 + 1) * 900,
            xp_b, M, 900, 600, 0);
        gru_layer<<<32 * GBLK, 256, 0, stream>>>(
            xp_f, xp_b,
            wbf + (size_t)l * 2 * 270000,
            b_hh + (size_t)l * 2 * 900,
            hbuf + (size_t)l * 2 * (2 * BB * HH),
            cnts + l * 32 * 16,
            xout);
    }

    // 6. stt / end projections (relu) from layer-2 output (in x0)
    gemm_nt_bias<<<dim3((FF + BN - 1) / BN, (M + BM - 1) / BM), 256, 0, stream>>>(
        x0, w_stt, b_stt, sttb, M, FF, 2 * HH, 1);
    gemm_nt_bias<<<dim3((FF + BN - 1) / BN, (M + BM - 1) / BM), 256, 0, stream>>>(
        x0, w_end, b_end, endb, M, FF, 2 * HH, 1);

    // 7. span scores
    span_score<<<PP * BB, 128, 0, stream>>>(sttb, endb, w_a, p_lens, finalb);

    // 8. log-softmax rows -> out
    log_softmax_rows<<<BB, 256, 0, stream>>>(out, finalb, PP * AA);
}

// Round 3
// 5724.175 us; speedup vs baseline: 7.6131x; 7.6131x over previous
//
#include <hip/hip_runtime.h>
#include <hip/hip_bf16.h>
#include <math.h>

// Problem dims
#define PP 400
#define QQ 30
#define BB 32
#define EE 300
#define HH 300
#define FF 300
#define AA 30
#define LL 2

typedef unsigned short ushort_t;
typedef unsigned int uint_t;

// ---------------------------------------------------------------------------
// Embedding gather: out[row, e] = embed[tok[row], e]
__global__ void gather_embed(const int* __restrict__ tok,
                             const float* __restrict__ embed,
                             float* __restrict__ out, int n_tok) {
    int i = blockIdx.x * blockDim.x + threadIdx.x;
    int n = n_tok * EE;
    if (i >= n) return;
    int row = i / EE, e = i - row * EE;
    out[i] = embed[(size_t)tok[row] * EE + e];
}

// ---------------------------------------------------------------------------
// C[M,N] = A[M,K] @ Bw[N,K]^T + bias[N], optional relu.
#define BM 64
#define BN 64
#define BK 16
__global__ void gemm_nt_bias(const float* __restrict__ A,
                             const float* __restrict__ Bw,
                             const float* __restrict__ bias,
                             float* __restrict__ C,
                             int M, int N, int K, int relu) {
    __shared__ float As[BK][BM];
    __shared__ float Bs[BK][BN];
    int tid = threadIdx.x;
    int row0 = blockIdx.y * BM;
    int col0 = blockIdx.x * BN;
    int tx = tid & 15, ty = tid >> 4;
    int lm = tid >> 2;          // 0..63
    int lk = (tid & 3) * 4;     // 0,4,8,12
    float acc[4][4] = {{0.f}};
    for (int k0 = 0; k0 < K; k0 += BK) {
        float4 av = make_float4(0.f, 0.f, 0.f, 0.f);
        int ar = row0 + lm;
        int kk = k0 + lk;
        if (ar < M) {
            if (kk + 3 < K) {
                av = *(const float4*)(A + (size_t)ar * K + kk);
            } else {
                float t0 = (kk + 0 < K) ? A[(size_t)ar * K + kk + 0] : 0.f;
                float t1 = (kk + 1 < K) ? A[(size_t)ar * K + kk + 1] : 0.f;
                float t2 = (kk + 2 < K) ? A[(size_t)ar * K + kk + 2] : 0.f;
                float t3 = (kk + 3 < K) ? A[(size_t)ar * K + kk + 3] : 0.f;
                av = make_float4(t0, t1, t2, t3);
            }
        }
        As[lk + 0][lm] = av.x; As[lk + 1][lm] = av.y;
        As[lk + 2][lm] = av.z; As[lk + 3][lm] = av.w;

        float4 bv = make_float4(0.f, 0.f, 0.f, 0.f);
        int br = col0 + lm;
        if (br < N) {
            if (kk + 3 < K) {
                bv = *(const float4*)(Bw + (size_t)br * K + kk);
            } else {
                float t0 = (kk + 0 < K) ? Bw[(size_t)br * K + kk + 0] : 0.f;
                float t1 = (kk + 1 < K) ? Bw[(size_t)br * K + kk + 1] : 0.f;
                float t2 = (kk + 2 < K) ? Bw[(size_t)br * K + kk + 2] : 0.f;
                float t3 = (kk + 3 < K) ? Bw[(size_t)br * K + kk + 3] : 0.f;
                bv = make_float4(t0, t1, t2, t3);
            }
        }
        Bs[lk + 0][lm] = bv.x; Bs[lk + 1][lm] = bv.y;
        Bs[lk + 2][lm] = bv.z; Bs[lk + 3][lm] = bv.w;
        __syncthreads();
        #pragma unroll
        for (int k = 0; k < BK; k++) {
            float a[4], b[4];
            #pragma unroll
            for (int i = 0; i < 4; i++) a[i] = As[k][ty * 4 + i];
            #pragma unroll
            for (int j = 0; j < 4; j++) b[j] = Bs[k][tx * 4 + j];
            #pragma unroll
            for (int i = 0; i < 4; i++) {
                #pragma unroll
                for (int j = 0; j < 4; j++) acc[i][j] += a[i] * b[j];
            }
        }
        __syncthreads();
    }
    #pragma unroll
    for (int i = 0; i < 4; i++) {
        int r = row0 + ty * 4 + i;
        if (r >= M) continue;
        #pragma unroll
        for (int j = 0; j < 4; j++) {
            int c = col0 + tx * 4 + j;
            if (c >= N) continue;
            float v = acc[i][j] + bias[c];
            if (relu) v = fmaxf(v, 0.f);
            C[(size_t)r * N + c] = v;
        }
    }
}

// ---------------------------------------------------------------------------
// scores + softmax over q per (p,b)
__global__ void scores_softmax(const float* __restrict__ ffp,
                               const float* __restrict__ ffq,
                               const float* __restrict__ p_mask,
                               const float* __restrict__ q_mask,
                               float* __restrict__ weights) {
    int blk = blockIdx.x;          // p*BB + b
    int p = blk / BB, b = blk - p * BB;
    __shared__ float fp[FF];
    __shared__ float sq[QQ];
    for (int f = threadIdx.x; f < FF; f += blockDim.x)
        fp[f] = ffp[(size_t)(p * BB + b) * FF + f];
    __syncthreads();
    int q = threadIdx.x;
    if (q < QQ) {
        const float* fq = ffq + (size_t)(q * BB + b) * FF;
        float s = 0.f;
        for (int f = 0; f < FF; f++) s += fp[f] * fq[f];
        s *= p_mask[p * BB + b] * q_mask[q * BB + b];
        sq[q] = s;
    }
    __syncthreads();
    if (q < QQ) {
        float m = -INFINITY;
        for (int k = 0; k < QQ; k++) m = fmaxf(m, sq[k]);
        float sum = 0.f;
        for (int k = 0; k < QQ; k++) sum += expf(sq[k] - m);
        weights[(size_t)b * PP * QQ + p * QQ + q] = expf(sq[q] - m) / sum;
    }
}

// ---------------------------------------------------------------------------
__global__ void align_concat(const float* __restrict__ weights,
                             const float* __restrict__ q_emb,
                             const float* __restrict__ p_emb,
                             float* __restrict__ x0) {
    int blk = blockIdx.x;          // p*BB + b
    int p = blk / BB, b = blk - p * BB;
    __shared__ float w[QQ];
    if (threadIdx.x < QQ)
        w[threadIdx.x] = weights[(size_t)b * PP * QQ + p * QQ + threadIdx.x];
    __syncthreads();
    for (int e = threadIdx.x; e < EE; e += blockDim.x) {
        float acc = 0.f;
        for (int q = 0; q < QQ; q++)
            acc += w[q] * q_emb[(size_t)(q * BB + b) * EE + e];
        size_t base = (size_t)(p * BB + b) * (2 * EE);
        x0[base + e] = p_emb[(size_t)(p * BB + b) * EE + e];
        x0[base + EE + e] = acc;
    }
}

// ---------------------------------------------------------------------------
// w_hh fp32 [4][900][300] -> bf16 (RNE) same layout
__global__ void convert_whh_bf16(const float* __restrict__ w,
                                 ushort_t* __restrict__ o) {
    int i = blockIdx.x * blockDim.x + threadIdx.x;
    if (i >= 4 * 900 * 300) return;
    uint_t u = __float_as_uint(w[i]);
    uint_t r = (u + 0x7fffu + ((u >> 16) & 1u)) >> 16;
    o[i] = (ushort_t)r;
}

// zero h double-buffers (both layers) and group counters
__global__ void init_gru(float* __restrict__ hbuf, int* __restrict__ cnt) {
    int i = blockIdx.x * blockDim.x + threadIdx.x;
    if (i < 2 * 2 * 2 * BB * HH) hbuf[i] = 0.f;
    if (i < 2 * 32 * 16) cnt[i] = 0;
}

// ---------------------------------------------------------------------------
// Persistent BiGRU layer: 400 steps in one launch.
// Grid = 320 blocks: 32 groups (2 dirs x 16 batch-pairs) x 10 blocks.
// Each block owns j-slice [j0, j0+30) for its 2 batches; its 90 w_hh rows
// (r/z/n gates) live in LDS as bf16 (row stride 151 dwords -> conflict-free).
//
// Sync protocol (R3, fence-free): h values are transported through RELAXED
// agent-scope atomics (write-through to the device coherence point; no
// buffer_inv / buffer_wbl2 cache maintenance is ever emitted). All h writers
// and the counter bump live in wave 0, so an explicit wave-local
// s_waitcnt(0) before the relaxed counter atomicAdd gives release ordering
// at the HW level. Consumers: relaxed poll -> __syncthreads -> relaxed
// atomic h loads (barrier prevents hoisting; HW issues in order).
#define GBLK 10
__global__ __launch_bounds__(256, 1) void gru_layer(
        const float* __restrict__ xp_f,   // [400][32][900]
        const float* __restrict__ xp_b,   // [400][32][900]
        const ushort_t* __restrict__ wbf, // [2][900][300] bf16, this layer
        const float* __restrict__ bhh,    // [2][900], this layer
        float* __restrict__ hbuf,         // [2][2][32][300], this layer
        int* __restrict__ cnts,           // [32][16], this layer
        float* __restrict__ out) {        // [400][32][600]
    int gid = blockIdx.x;
    int group = gid / GBLK;          // 0..31
    int blkin = gid - group * GBLK;  // 0..9
    int dir = group >> 4;
    int b0 = (group & 15) * 2;
    int j0 = blkin * 30;
    const float* xp = dir ? xp_b : xp_f;
    const float* bhh_d = bhh + dir * 900;
    int* cnt = cnts + group * 16;

    __shared__ ushort_t sW[90 * 302];    // row stride 302 bf16 = 151 dwords
    __shared__ float sh[2][300];
    __shared__ float sgh[2][90];
    uint_t* sWu = (uint_t*)sW;

    int tid = threadIdx.x;

    // one-time: stage this block's 90 weight rows into LDS
    {
        const uint_t* wsrc = (const uint_t*)(wbf + (size_t)dir * 270000);
        for (int d = tid; d < 90 * 150; d += 256) {
            int r = d / 150, k = d - r * 150;
            int gr = (r < 30) ? (j0 + r)
                   : (r < 60) ? (300 + j0 + r - 30)
                              : (600 + j0 + r - 60);
            sWu[r * 151 + k] = wsrc[gr * 150 + k];
        }
    }
    // per-thread constants
    int bb = tid / 90, rr = tid - (tid / 90) * 90;   // dot phase (tid<180)
    float bias = 0.f;
    if (tid < 180) {
        int gr = (rr < 30) ? (j0 + rr)
               : (rr < 60) ? (300 + j0 + rr - 30)
                           : (600 + j0 + rr - 60);
        bias = bhh_d[gr];
    }
    __syncthreads();

    for (int s = 0; s < PP; s++) {
        int te = dir ? (PP - 1 - s) : s;
        // prefetch this step's xp gate inputs (independent of h / sync)
        float xrv = 0.f, xzv = 0.f, xnv = 0.f;
        if (tid < 60) {
            const float* xq = xp + ((size_t)te * BB + (b0 + tid / 30)) * 900
                              + j0 + (tid - (tid / 30) * 30);
            xrv = xq[0]; xzv = xq[300]; xnv = xq[600];
        }
        // wait for h[s&1] to be complete (relaxed poll only; no fences)
        if (s > 0) {
            if (tid == 0) {
                while (__hip_atomic_load(cnt, __ATOMIC_RELAXED,
                                         __HIP_MEMORY_SCOPE_AGENT) < GBLK * s)
                    __builtin_amdgcn_s_sleep(1);
            }
            __syncthreads();
        }
        // stage h (600 floats for our 2 batches) via relaxed agent atomics
        {
            const float* hr = hbuf + (size_t)(s & 1) * (2 * BB * HH)
                              + (size_t)(dir * BB + b0) * HH;
            for (int d = tid; d < 600; d += 256)
                sh[d / 300][d - (d / 300) * 300] =
                    __hip_atomic_load(&hr[d], __ATOMIC_RELAXED,
                                      __HIP_MEMORY_SCOPE_AGENT);
        }
        __syncthreads();
        // 90 rows x 2 batches of 300-MAC dots, weights from LDS (bf16)
        if (tid < 180) {
            const uint_t* wrow = sWu + rr * 151;
            const float2* hp = (const float2*)sh[bb];
            float acc = 0.f;
            #pragma unroll 10
            for (int k = 0; k < 150; k++) {
                uint_t wp = wrow[k];
                float2 hv = hp[k];
                acc = fmaf(__uint_as_float(wp << 16), hv.x, acc);
                acc = fmaf(__uint_as_float(wp & 0xffff0000u), hv.y, acc);
            }
            sgh[bb][rr] = acc + bias;
        }
        __syncthreads();
        // gate math + h update for our 60 (b,j) pairs (all in wave 0)
        if (tid < 60) {
            int gb = tid / 30, jj = tid - gb * 30;
            int bg = b0 + gb;
            float r = 1.f / (1.f + expf(-(xrv + sgh[gb][jj])));
            float z = 1.f / (1.f + expf(-(xzv + sgh[gb][30 + jj])));
            float n = tanhf(xnv + r * sgh[gb][60 + jj]);
            float hn = (1.f - z) * n + z * sh[gb][j0 + jj];
            __hip_atomic_store(
                &hbuf[(size_t)((s + 1) & 1) * (2 * BB * HH)
                      + (size_t)(dir * BB + bg) * HH + j0 + jj],
                hn, __ATOMIC_RELAXED, __HIP_MEMORY_SCOPE_AGENT);
            out[((size_t)te * BB + bg) * (2 * HH) + dir * HH + j0 + jj] = hn;
        }
        // wave-local drain: h stores (wave 0) acked at coherence point,
        // then publish. No cache-maintenance instructions emitted.
        __builtin_amdgcn_s_waitcnt(0);
        if (tid == 0)
            __hip_atomic_fetch_add(cnt, 1, __ATOMIC_RELAXED,
                                   __HIP_MEMORY_SCOPE_AGENT);
        __syncthreads();
    }
}

// ---------------------------------------------------------------------------
__global__ void span_score(const float* __restrict__ stt,
                           const float* __restrict__ endv,
                           const float* __restrict__ w_a,
                           const int* __restrict__ p_lens,
                           float* __restrict__ final_) {
    int blk = blockIdx.x;          // p*BB + b
    int p = blk / BB, b = blk - p * BB;
    __shared__ float ss[FF];
    __shared__ float wa[FF];
    for (int f = threadIdx.x; f < FF; f += blockDim.x) {
        ss[f] = stt[(size_t)(p * BB + b) * FF + f];
        wa[f] = w_a[f];
    }
    __syncthreads();
    int lane = threadIdx.x & 63, wv = threadIdx.x >> 6;
    int plen = p_lens[b];
    for (int j = wv; j < AA; j += 2) {
        float acc = 0.f;
        int pe = p + j;
        if (pe < PP) {
            const float* ev = endv + (size_t)(pe * BB + b) * FF;
            for (int f = lane; f < FF; f += 64)
                acc += fmaxf(ss[f] + ev[f], 0.f) * wa[f];
        } else {
            for (int f = lane; f < FF; f += 64)
                acc += fmaxf(ss[f], 0.f) * wa[f];
        }
        #pragma unroll
        for (int off = 32; off; off >>= 1) acc += __shfl_down(acc, off);
        if (lane == 0) {
            float v = (pe < plen) ? acc : 0.f;
            final_[(size_t)b * (PP * AA) + p * AA + j] = v;
        }
    }
}

// ---------------------------------------------------------------------------
__global__ void log_softmax_rows(float* __restrict__ out,
                                 const float* __restrict__ final_, int n) {
    int b = blockIdx.x;
    const float* row = final_ + (size_t)b * n;
    __shared__ float red[256];
    float m = -INFINITY;
    for (int i = threadIdx.x; i < n; i += 256) m = fmaxf(m, row[i]);
    red[threadIdx.x] = m;
    __syncthreads();
    for (int s = 128; s; s >>= 1) {
        if (threadIdx.x < s) red[threadIdx.x] = fmaxf(red[threadIdx.x], red[threadIdx.x + s]);
        __syncthreads();
    }
    m = red[0];
    __syncthreads();
    float sum = 0.f;
    for (int i = threadIdx.x; i < n; i += 256) sum += expf(row[i] - m);
    red[threadIdx.x] = sum;
    __syncthreads();
    for (int s = 128; s; s >>= 1) {
        if (threadIdx.x < s) red[threadIdx.x] += red[threadIdx.x + s];
        __syncthreads();
    }
    float lse = m + logf(red[0]);
    for (int i = threadIdx.x; i < n; i += 256) out[(size_t)b * n + i] = row[i] - lse;
}

// ---------------------------------------------------------------------------
extern "C" void kernel_launch(void* const* d_in, const int* in_sizes, int n_in,
                              void* d_out, int out_size, void* d_ws, size_t ws_size,
                              hipStream_t stream) {
    (void)in_sizes; (void)n_in; (void)out_size; (void)ws_size;
    const int*   p_tok  = (const int*)d_in[0];
    const int*   q_tok  = (const int*)d_in[1];
    const float* p_mask = (const float*)d_in[2];
    const float* q_mask = (const float*)d_in[3];
    const int*   p_lens = (const int*)d_in[4];
    const float* embed   = (const float*)d_in[6];
    const float* w_align = (const float*)d_in[7];
    const float* b_align = (const float*)d_in[8];
    const float* w_ih    = (const float*)d_in[9];    // [2,2,900,600]
    const float* w_hh    = (const float*)d_in[10];   // [2,2,900,300]
    const float* b_ih    = (const float*)d_in[11];   // [2,2,900]
    const float* b_hh    = (const float*)d_in[12];   // [2,2,900]
    const float* w_stt   = (const float*)d_in[13];
    const float* b_stt   = (const float*)d_in[14];
    const float* w_end   = (const float*)d_in[15];
    const float* b_end   = (const float*)d_in[16];
    const float* w_a     = (const float*)d_in[17];
    float* out = (float*)d_out;
    float* ws = (float*)d_ws;

    size_t off = 0;
    float* p_emb = ws + off;  off += (size_t)PP * BB * EE;       // 3,840,000
    float* ff_p  = ws + off;  off += (size_t)PP * BB * FF;       // 3,840,000
    float* q_emb = ws + off;  off += (size_t)QQ * BB * EE;       //   288,000
    float* ff_q  = ws + off;  off += (size_t)QQ * BB * FF;       //   288,000
    float* scores= ws + off;  off += (size_t)BB * PP * QQ;       //   384,000
    float* x0    = ws + off;  off += (size_t)PP * BB * 2 * EE;   // 7,680,000
    float* xp_f  = ws + off;  off += (size_t)PP * BB * 900;      // 11,520,000
    float* xp_b  = ws + off;  off += (size_t)PP * BB * 900;      // 11,520,000
    ushort_t* wbf = (ushort_t*)(ws + off); off += 540000;        // 4*900*300 bf16
    float* hbuf  = ws + off;  off += (size_t)2 * 2 * 2 * BB * HH; //  76,800
    int*   cnts  = (int*)(ws + off); off += 2 * 32 * 16;         //     1,024
    float* x1    = p_emb;       // aliases p_emb+ff_p (dead by GRU time)
    float* sttb  = xp_f;        // aliases xp (dead after layer-2 recurrence)
    float* endb  = xp_f + (size_t)PP * BB * FF;
    float* finalb= scores;

    const int M = PP * BB;      // 12800
    const int Mq = QQ * BB;     // 960

    // prep: bf16 recurrent weights + zero h/counters
    convert_whh_bf16<<<(4 * 900 * 300 + 255) / 256, 256, 0, stream>>>(w_hh, wbf);
    init_gru<<<(2 * 2 * 2 * BB * HH + 255) / 256, 256, 0, stream>>>(hbuf, cnts);

    // 1. embedding gathers
    gather_embed<<<(M * EE + 255) / 256, 256, 0, stream>>>(p_tok, embed, p_emb, M);
    gather_embed<<<(Mq * EE + 255) / 256, 256, 0, stream>>>(q_tok, embed, q_emb, Mq);

    // 2. aligned-attention projections (relu)
    gemm_nt_bias<<<dim3((FF + BN - 1) / BN, (M + BM - 1) / BM), 256, 0, stream>>>(
        p_emb, w_align, b_align, ff_p, M, FF, EE, 1);
    gemm_nt_bias<<<dim3((FF + BN - 1) / BN, (Mq + BM - 1) / BM), 256, 0, stream>>>(
        q_emb, w_align, b_align, ff_q, Mq, FF, EE, 1);

    // 3. scores + softmax over q
    scores_softmax<<<PP * BB, 64, 0, stream>>>(ff_p, ff_q, p_mask, q_mask, scores);

    // 4. q_align + concat -> x0 = p_star [P,B,600]
    align_concat<<<PP * BB, 256, 0, stream>>>(scores, q_emb, p_emb, x0);

    // 5. BiGRU, 2 layers: batched xp GEMMs + one persistent kernel per layer
    for (int l = 0; l < LL; l++) {
        const float* xin = (l == 0) ? x0 : x1;
        float* xout = (l == 0) ? x1 : x0;
        gemm_nt_bias<<<dim3((900 + BN - 1) / BN, (M + BM - 1) / BM), 256, 0, stream>>>(
            xin, w_ih + (size_t)(l * 2 + 0) * 900 * 600, b_ih + (l * 2 + 0) * 900,
            xp_f, M, 900, 600, 0);
        gemm_nt_bias<<<dim3((900 + BN - 1) / BN, (M + BM - 1) / BM), 256, 0, stream>>>(
            xin, w_ih + (size_t)(l * 2 + 1) * 900 * 600, b_ih + (l * 2 + 1) * 900,
            xp_b, M, 900, 600, 0);
        gru_layer<<<32 * GBLK, 256, 0, stream>>>(
            xp_f, xp_b,
            wbf + (size_t)l * 2 * 270000,
            b_hh + (size_t)l * 2 * 900,
            hbuf + (size_t)l * 2 * (2 * BB * HH),
            cnts + l * 32 * 16,
            xout);
    }

    // 6. stt / end projections (relu) from layer-2 output (in x0)
    gemm_nt_bias<<<dim3((FF + BN - 1) / BN, (M + BM - 1) / BM), 256, 0, stream>>>(
        x0, w_stt, b_stt, sttb, M, FF, 2 * HH, 1);
    gemm_nt_bias<<<dim3((FF + BN - 1) / BN, (M + BM - 1) / BM), 256, 0, stream>>>(
        x0, w_end, b_end, endb, M, FF, 2 * HH, 1);

    // 7. span scores
    span_score<<<PP * BB, 128, 0, stream>>>(sttb, endb, w_a, p_lens, finalb);

    // 8. log-softmax rows -> out
    log_softmax_rows<<<BB, 256, 0, stream>>>(out, finalb, PP * AA);
}